// Round 14
// baseline (31.942 us; speedup 1.0000x reference)
//
#include <hip/hip_runtime.h>
#include <hip/hip_bf16.h>
#include <math.h>

#define QN 128
#define SN 128
#define HN 32
#define CN (QN * SN)
#define RB 32      // rows per block
#define QB 4       // consecutive q's per block (one per wave)
#define LROW 136   // halves per LDS row: 128 + 8 pad -> bank-quad=(chunk+row)%8

using half8   = __attribute__((ext_vector_type(8))) _Float16;
using half4v  = __attribute__((ext_vector_type(4))) _Float16;
using floatx4 = __attribute__((ext_vector_type(4))) float;

// MFMA grouped-GEMM with WIDE-GRANULE x reads. Block: 256 threads (4 waves),
// q0..q0+3 x 32 rows; wave w computes q=q0+w for all 32 rows (two 16-row
// M-tiles). KEY CHANGE vs R8-R13 (all pinned ~4.6 TB/s): the block's x
// footprint per row is 2 KB CONTIGUOUS (4 q-slices), staged linearly --
// each wave-instruction reads 1 KB contiguous instead of 16 scattered 128-B
// lines at 64-KB stride. Tests the DRAM-page/granule-efficiency theory.
// LDS [q][row][136h]: 272-B row stride => A-frag ds_read_b128 quarter-waves
// (fixed koct, nA=0..15) hit each bank-quad exactly 2x = free (m136);
// staging ds_write_b64 is consecutive 8B/lane = conflict-free. fp32->fp16
// converts happen at staging (out of the MFMA loop).
__global__ __launch_bounds__(256, 4)
void divenc_kernel(const float* __restrict__ x,
                   const float* __restrict__ W1,
                   const float* __restrict__ b1,
                   const float* __restrict__ W2,
                   const float* __restrict__ b2,
                   float* __restrict__ out) {
  const int q0   = blockIdx.y * QB;
  const int r0   = blockIdx.x * RB;
  const int tid  = threadIdx.x;
  const int lane = tid & 63;
  const int wid  = __builtin_amdgcn_readfirstlane(tid >> 6);
  const int q    = q0 + wid;          // this wave's q (uniform)
  const int nA   = lane & 15;         // A-row within M-tile / C col
  const int koct = lane >> 4;         // k-octet 0..3

  __shared__ _Float16 xs[QB * RB * LROW];  // 34816 B

  // ---- stage x: block footprint = rows r0..r0+31, bytes [q0*2048, q0*2048+2048)
  // per row. Linear read: f = i*256+tid indexes float4s; per instruction the
  // 64 lanes cover 1 KB contiguous. Convert to fp16, ds_write_b64.
  {
    const float* xb = x + (size_t)r0 * CN + (size_t)q0 * SN;
    #pragma unroll
    for (int i = 0; i < 16; ++i) {
      const int f  = i * 256 + tid;
      const int r  = f >> 7;          // row (128 float4s = 2 KB per row)
      const int su = f & 127;
      const int qi = su >> 5;         // q within block
      const int c  = su & 31;         // float4 within q-slice
      const float4 v = *reinterpret_cast<const float4*>(
          xb + (size_t)r * CN + qi * SN + c * 4);
      half4v h;
      h[0] = (_Float16)v.x; h[1] = (_Float16)v.y;
      h[2] = (_Float16)v.z; h[3] = (_Float16)v.w;
      *reinterpret_cast<half4v*>(&xs[qi * (RB * LROW) + r * LROW + c * 4]) = h;
    }
  }

  // ---- W1 B-frags (overlap with staging loads): lane holds
  // W1[q][kk*32+koct*8+i][n0*16+nA] as fp16. Wave-uniform q.
  const float* __restrict__ w1q = W1 + (size_t)q * (SN * HN);
  half8 bf[2][4];
  #pragma unroll
  for (int n0 = 0; n0 < 2; ++n0) {
    #pragma unroll
    for (int kk = 0; kk < 4; ++kk) {
      #pragma unroll
      for (int i = 0; i < 8; ++i) {
        const int k = kk * 32 + koct * 8 + i;
        bf[n0][kk][i] = (_Float16)w1q[k * HN + n0 * 16 + nA];
      }
    }
  }
  const float b1a = b1[q * HN + nA],  b1b = b1[q * HN + 16 + nA];
  const float w2a = W2[q * HN + nA],  w2b = W2[q * HN + 16 + nA];
  const float b2q = b2[q];

  __syncthreads();

  // ---- MFMA: A-frag = ds_read_b128 of 8 halves, already fp16.
  const _Float16* myq = &xs[wid * (RB * LROW)];
  const floatx4 z = {0.f, 0.f, 0.f, 0.f};
  floatx4 acc[2][2];
  acc[0][0] = z; acc[0][1] = z; acc[1][0] = z; acc[1][1] = z;

  #pragma unroll
  for (int mt = 0; mt < 2; ++mt) {
    const _Float16* rowb = myq + (mt * 16 + nA) * LROW;
    #pragma unroll
    for (int kk = 0; kk < 4; ++kk) {
      const half8 af = *reinterpret_cast<const half8*>(
          rowb + (kk * 4 + koct) * 8);
      acc[mt][0] = __builtin_amdgcn_mfma_f32_16x16x32_f16(af, bf[0][kk], acc[mt][0], 0, 0, 0);
      acc[mt][1] = __builtin_amdgcn_mfma_f32_16x16x32_f16(af, bf[1][kk], acc[mt][1], 0, 0, 0);
    }
  }

  // ---- epilogue. C/D: col = nA, row(in tile) = koct*4 + reg.
  #pragma unroll
  for (int mt = 0; mt < 2; ++mt) {
    #pragma unroll
    for (int reg = 0; reg < 4; ++reg) {
      float v0 = acc[mt][0][reg] + b1a;
      v0 = v0 > 0.f ? v0 : expm1f(v0);
      float v1 = acc[mt][1][reg] + b1b;
      v1 = v1 > 0.f ? v1 : expm1f(v1);
      float t = fmaf(v0, w2a, v1 * w2b);
      t += __shfl_xor(t, 1);
      t += __shfl_xor(t, 2);
      t += __shfl_xor(t, 4);
      t += __shfl_xor(t, 8);
      if (nA == 0) {
        const int row = r0 + mt * 16 + koct * 4 + reg;
        out[(size_t)row * QN + q] = t + b2q;
      }
    }
  }
}

extern "C" void kernel_launch(void* const* d_in, const int* in_sizes, int n_in,
                              void* d_out, int out_size, void* d_ws, size_t ws_size,
                              hipStream_t stream) {
  const float* x  = (const float*)d_in[0];
  const float* W1 = (const float*)d_in[1];
  const float* b1 = (const float*)d_in[2];
  const float* W2 = (const float*)d_in[3];
  const float* b2 = (const float*)d_in[4];
  float* out = (float*)d_out;

  const int B = in_sizes[0] / CN;      // 2048
  dim3 grid(B / RB, QN / QB);          // 64 row-groups x 32 q-quads
  divenc_kernel<<<grid, 256, 0, stream>>>(x, W1, b1, W2, b2, out);
}